// Round 2
// baseline (255.526 us; speedup 1.0000x reference)
//
#include <hip/hip_runtime.h>

#define N_FLOWS 20
#define DIM 4
#define ITEMS 4            // samples per thread per tile (one rcp-quad per flow)
#define BLOCK 256
#define PBLOCKS 2048       // persistent blocks: 8 workgroups/CU on 256 CUs
#define TILE (BLOCK * ITEMS)   // 1024 samples (= 1024 float4) per tile

typedef float v2f __attribute__((ext_vector_type(2)));

// ---------------------------------------------------------------------------
// Setup: one tiny block precomputes per-flow constants for the d-space
// recurrence. d_f := x - x0_f;  s = 1 + beta/(alpha + ||d_f||);
// d_{f+1} = s*d_f + c_f, with c_f = x0_f - x0_{f+1} (f<19), c_19 = x0_19
// so the final update directly produces x_20.
// ws layout per flow f (8 floats): [c.x,c.y,c.z,c.w, alpha, beta, 0, 0]
// slot f==N_FLOWS: [x0_0 (4 floats), 0,0,0,0]  (for d_0 init)
// ---------------------------------------------------------------------------
__global__ void radial_setup(const float* __restrict__ x0s,
                             const float* __restrict__ alpha_primes,
                             const float* __restrict__ beta_primes,
                             float* __restrict__ ws) {
    int f = threadIdx.x;
    if (f < N_FLOWS) {
        float alpha = __logf(1.0f + __expf(alpha_primes[f]));
        float beta  = __logf(1.0f + __expf(beta_primes[f])) - alpha;
        float* p = ws + 8 * f;
        const bool last = (f == N_FLOWS - 1);
#pragma unroll
        for (int j = 0; j < 4; ++j)
            p[j] = x0s[4 * f + j] - (last ? 0.0f : x0s[4 * (f + 1) + j]);
        p[4] = alpha;
        p[5] = beta;
        p[6] = 0.0f;
        p[7] = 0.0f;
    } else if (f == N_FLOWS) {
        float* p = ws + 8 * N_FLOWS;
        p[0] = x0s[0]; p[1] = x0s[1]; p[2] = x0s[2]; p[3] = x0s[3];
        p[4] = 0.0f; p[5] = 0.0f; p[6] = 0.0f; p[7] = 0.0f;
    }
}

// ---------------------------------------------------------------------------
// 20 chained flows on ITEMS samples held in (a,b) v2f register pairs.
// Per flow: 4x {pk_mul, pk_fma, add, v_sqrt, add} to form D_i = alpha + r_i,
// then ONE v_rcp via quad batch-inversion (9 muls), then 4x {fma, 2x pk_fma}.
// Trans cost/item: 16 (sqrt) + 4 (rcp/4) vs 32 before.
// ---------------------------------------------------------------------------
__device__ __forceinline__ void flow_chain(v2f a[ITEMS], v2f b[ITEMS],
                                           const float4* __restrict__ P) {
#pragma unroll
    for (int f = 0; f < N_FLOWS; ++f) {
        float4 c  = P[2 * f];       // uniform -> s_load
        float4 ab = P[2 * f + 1];
        v2f c01 = (v2f){c.x, c.y};
        v2f c23 = (v2f){c.z, c.w};
        float alpha = ab.x, beta = ab.y;

        float D[ITEMS];
#pragma unroll
        for (int i = 0; i < ITEMS; ++i) {
            v2f q = a[i] * a[i];          // v_pk_mul_f32
            q += b[i] * b[i];             // v_pk_fma_f32
            float r2 = q.x + q.y;         // v_add_f32
            D[i] = alpha + __builtin_amdgcn_sqrtf(r2);   // v_sqrt + v_add
        }
        // quad batch inversion: one v_rcp for 4 denominators
        float p1  = D[0] * D[1];
        float p2  = p1 * D[2];
        float p3  = p2 * D[3];
        float inv = __builtin_amdgcn_rcpf(p3);
        float i3 = inv * p2;              // 1/D3
        float w2 = inv * D[3];            // 1/(D0 D1 D2)
        float i2 = w2 * p1;               // 1/D2
        float w1 = w2 * D[2];             // 1/(D0 D1)
        float i1 = w1 * D[0];             // 1/D1
        float i0 = w1 * D[1];             // 1/D0
        float invD[ITEMS] = {i0, i1, i2, i3};
#pragma unroll
        for (int i = 0; i < ITEMS; ++i) {
            float s = __builtin_fmaf(beta, invD[i], 1.0f);  // v_fma
            v2f sv = (v2f){s, s};
            a[i] = sv * a[i] + c01;       // v_pk_fma_f32 (d = s*d + c)
            b[i] = sv * b[i] + c23;
        }
    }
}

__device__ __forceinline__ void compute_store(const float4 (&buf)[ITEMS],
                                              unsigned idx, v2f z01, v2f z23,
                                              const float4* __restrict__ P,
                                              float4* __restrict__ Ov) {
    v2f a[ITEMS], b[ITEMS];
#pragma unroll
    for (int i = 0; i < ITEMS; ++i) {     // d_0 = x - x0_0; buf regs die here,
        a[i] = (v2f){buf[i].x, buf[i].y} - z01;   // freeing them for the next prefetch
        b[i] = (v2f){buf[i].z, buf[i].w} - z23;
    }
    flow_chain(a, b, P);
#pragma unroll
    for (int i = 0; i < ITEMS; ++i) {
        float4 v;
        v.x = a[i].x; v.y = a[i].y; v.z = b[i].x; v.w = b[i].y;
        Ov[idx + i * BLOCK] = v;
    }
}

// ---------------------------------------------------------------------------
// Persistent main: each block owns T consecutive tiles, register-double-
// buffered (A/B ping-pong, manually unrolled so all reg indices are static).
// Tile t+1's global loads are issued BEFORE tile t's compute, so HBM latency
// and bandwidth hide under the ~40us of VALU work instead of serializing.
// ---------------------------------------------------------------------------
__global__ __launch_bounds__(BLOCK, 8) void radial_main(
    const float4* __restrict__ Xv,
    const float4* __restrict__ P,
    float4* __restrict__ Ov,
    int T) {
    float4 z = P[2 * N_FLOWS];            // x0_0 (uniform -> s_load)
    v2f z01 = (v2f){z.x, z.y};
    v2f z23 = (v2f){z.z, z.w};

    const unsigned tbase = (unsigned)blockIdx.x * (unsigned)T;
    const unsigned lane  = threadIdx.x;

    float4 A[ITEMS], B[ITEMS];
    {
        unsigned idx = tbase * TILE + lane;
#pragma unroll
        for (int i = 0; i < ITEMS; ++i) A[i] = Xv[idx + i * BLOCK];
    }

    int t = 0;
    for (;;) {
        {   // compute tile t from A; prefetch tile t+1 into B first
            unsigned idx = (tbase + t) * TILE + lane;
            if (t + 1 < T) {
                unsigned idn = idx + TILE;
#pragma unroll
                for (int i = 0; i < ITEMS; ++i) B[i] = Xv[idn + i * BLOCK];
            }
            compute_store(A, idx, z01, z23, P, Ov);
        }
        if (++t >= T) break;
        {   // compute tile t from B; prefetch tile t+1 into A first
            unsigned idx = (tbase + t) * TILE + lane;
            if (t + 1 < T) {
                unsigned idn = idx + TILE;
#pragma unroll
                for (int i = 0; i < ITEMS; ++i) A[i] = Xv[idn + i * BLOCK];
            }
            compute_store(B, idx, z01, z23, P, Ov);
        }
        if (++t >= T) break;
    }
}

// Generic tail: one guarded sample per thread (grid is 0 for BATCH=2^23).
__global__ void radial_tail(const float4* __restrict__ Xv,
                            const float4* __restrict__ P,
                            float4* __restrict__ Ov,
                            int start, int batch) {
    int idx = start + blockIdx.x * blockDim.x + threadIdx.x;
    if (idx >= batch) return;
    float4 z = P[2 * N_FLOWS];
    float4 v = Xv[idx];
    float dx = v.x - z.x, dy = v.y - z.y, dz = v.z - z.z, dw = v.w - z.w;
#pragma unroll
    for (int f = 0; f < N_FLOWS; ++f) {
        float4 c  = P[2 * f];
        float4 ab = P[2 * f + 1];
        float r2 = dx * dx + dy * dy + dz * dz + dw * dw;
        float r  = __builtin_amdgcn_sqrtf(r2);
        float s  = __builtin_fmaf(ab.y, __builtin_amdgcn_rcpf(ab.x + r), 1.0f);
        dx = s * dx + c.x; dy = s * dy + c.y;
        dz = s * dz + c.z; dw = s * dw + c.w;
    }
    float4 o; o.x = dx; o.y = dy; o.z = dz; o.w = dw;
    Ov[idx] = o;
}

extern "C" void kernel_launch(void* const* d_in, const int* in_sizes, int n_in,
                              void* d_out, int out_size, void* d_ws, size_t ws_size,
                              hipStream_t stream) {
    const float* X   = (const float*)d_in[0];
    const float* x0s = (const float*)d_in[1];
    const float* ap  = (const float*)d_in[2];
    const float* bp  = (const float*)d_in[3];
    float* out = (float*)d_out;
    float* ws  = (float*)d_ws;

    int batch = in_sizes[0] / DIM;     // 8388608
    int tiles = batch / TILE;          // 8192 for BATCH=2^23

    radial_setup<<<1, 64, 0, stream>>>(x0s, ap, bp, ws);

    int done = 0;
    if (tiles >= PBLOCKS) {
        int T = tiles / PBLOCKS;       // 4
        radial_main<<<PBLOCKS, BLOCK, 0, stream>>>(
            (const float4*)X, (const float4*)ws, (float4*)out, T);
        done = PBLOCKS * T * TILE;
    } else if (tiles > 0) {
        radial_main<<<tiles, BLOCK, 0, stream>>>(
            (const float4*)X, (const float4*)ws, (float4*)out, 1);
        done = tiles * TILE;
    }

    int rem = batch - done;
    if (rem > 0)
        radial_tail<<<(rem + 255) / 256, 256, 0, stream>>>(
            (const float4*)X, (const float4*)ws, (float4*)out, done, batch);
}

// Round 5
// 254.232 us; speedup vs baseline: 1.0051x; 1.0051x over previous
//
#include <hip/hip_runtime.h>

#define N_FLOWS 20
#define DIM 4
#define ITEMS 4            // samples per thread per tile (one rcp-quad per flow)
#define BLOCK 256
#define PBLOCKS 1024       // persistent blocks: exactly 4 workgroups/CU on 256 CUs
#define TILE (BLOCK * ITEMS)   // 1024 float4 samples per tile

typedef float v2f __attribute__((ext_vector_type(2)));
typedef float v4f __attribute__((ext_vector_type(4)));   // native vector: OK for
                                                         // __builtin_nontemporal_store
                                                         // (HIP float4 class is NOT)

// ---------------------------------------------------------------------------
// Setup: one tiny block precomputes per-flow constants for the d-space
// recurrence. d_f := x - x0_f;  s = 1 + beta/(alpha + ||d_f||);
// d_{f+1} = s*d_f + c_f, with c_f = x0_f - x0_{f+1} (f<19), c_19 = x0_19
// so the final update directly produces x_20.
// ws layout per flow f (8 floats): [c.x,c.y,c.z,c.w, alpha, beta, 0, 0]
// slot f==N_FLOWS: [x0_0 (4 floats), 0,0,0,0]  (for d_0 init)
// ---------------------------------------------------------------------------
__global__ void radial_setup(const float* __restrict__ x0s,
                             const float* __restrict__ alpha_primes,
                             const float* __restrict__ beta_primes,
                             float* __restrict__ ws) {
    int f = threadIdx.x;
    if (f < N_FLOWS) {
        float alpha = __logf(1.0f + __expf(alpha_primes[f]));
        float beta  = __logf(1.0f + __expf(beta_primes[f])) - alpha;
        float* p = ws + 8 * f;
        const bool last = (f == N_FLOWS - 1);
#pragma unroll
        for (int j = 0; j < 4; ++j)
            p[j] = x0s[4 * f + j] - (last ? 0.0f : x0s[4 * (f + 1) + j]);
        p[4] = alpha;
        p[5] = beta;
        p[6] = 0.0f;
        p[7] = 0.0f;
    } else if (f == N_FLOWS) {
        float* p = ws + 8 * N_FLOWS;
        p[0] = x0s[0]; p[1] = x0s[1]; p[2] = x0s[2]; p[3] = x0s[3];
        p[4] = 0.0f; p[5] = 0.0f; p[6] = 0.0f; p[7] = 0.0f;
    }
}

// ---------------------------------------------------------------------------
// Everything macro-expanded into ONE function scope with NAMED variables:
// no local arrays, no array-reference args -> nothing for SROA to miss,
// buffers provably live in VGPRs (round-2 lesson: the by-reference array
// version went to scratch, +57 MB of spill traffic, zero speedup).
// Round-3 lesson: no token-pasting before member access; round-4 lesson:
// NT stores need native clang vectors, not HIP_vector_type.
// ---------------------------------------------------------------------------

// Load one tile into named buffer regs V0..V3.
#define LOADT(V0, V1, V2, V3, IDXV)               \
    do {                                          \
        V0 = Xv[(IDXV)];                          \
        V1 = Xv[(IDXV) + BLOCK];                  \
        V2 = Xv[(IDXV) + 2 * BLOCK];              \
        V3 = Xv[(IDXV) + 3 * BLOCK];              \
    } while (0)

// Run the 20-flow chain on buffer V0..V3 and store results (non-temporal:
// output is never re-read; keep it from evicting the L3-resident input).
// Per flow: 4x {pk_mul, pk_fma, add, v_sqrt, add} to form D_i = alpha + r_i,
// one shared v_rcp via quad batch-inversion (9 muls), 4x {fma, 2x pk_fma}.
#define COMPSTORE(V0, V1, V2, V3, IDXV)                                        \
    do {                                                                       \
        v2f a0 = (v2f){V0.x, V0.y} - z01;                                      \
        v2f b0 = (v2f){V0.z, V0.w} - z23;                                      \
        v2f a1 = (v2f){V1.x, V1.y} - z01;                                      \
        v2f b1 = (v2f){V1.z, V1.w} - z23;                                      \
        v2f a2 = (v2f){V2.x, V2.y} - z01;                                      \
        v2f b2 = (v2f){V2.z, V2.w} - z23;                                      \
        v2f a3 = (v2f){V3.x, V3.y} - z01;                                      \
        v2f b3 = (v2f){V3.z, V3.w} - z23;                                      \
        _Pragma("unroll")                                                      \
        for (int f = 0; f < N_FLOWS; ++f) {                                    \
            float4 c  = P[2 * f];        /* uniform -> s_load */               \
            float4 ab = P[2 * f + 1];                                          \
            v2f c01 = (v2f){c.x, c.y};                                         \
            v2f c23 = (v2f){c.z, c.w};                                         \
            float alpha = ab.x, beta = ab.y;                                   \
            v2f q0 = a0 * a0; q0 += b0 * b0;                                   \
            v2f q1 = a1 * a1; q1 += b1 * b1;                                   \
            v2f q2 = a2 * a2; q2 += b2 * b2;                                   \
            v2f q3 = a3 * a3; q3 += b3 * b3;                                   \
            float D0 = alpha + __builtin_amdgcn_sqrtf(q0.x + q0.y);            \
            float D1 = alpha + __builtin_amdgcn_sqrtf(q1.x + q1.y);            \
            float D2 = alpha + __builtin_amdgcn_sqrtf(q2.x + q2.y);            \
            float D3 = alpha + __builtin_amdgcn_sqrtf(q3.x + q3.y);            \
            float p1  = D0 * D1;                                               \
            float p2  = p1 * D2;                                               \
            float p3  = p2 * D3;                                               \
            float inv = __builtin_amdgcn_rcpf(p3);                             \
            float i3 = inv * p2;        /* 1/D3 */                             \
            float w2 = inv * D3;        /* 1/(D0 D1 D2) */                     \
            float i2 = w2 * p1;         /* 1/D2 */                             \
            float w1 = w2 * D2;         /* 1/(D0 D1) */                        \
            float i1 = w1 * D0;         /* 1/D1 */                             \
            float i0 = w1 * D1;         /* 1/D0 */                             \
            float s0 = __builtin_fmaf(beta, i0, 1.0f);                         \
            float s1 = __builtin_fmaf(beta, i1, 1.0f);                         \
            float s2 = __builtin_fmaf(beta, i2, 1.0f);                         \
            float s3 = __builtin_fmaf(beta, i3, 1.0f);                         \
            v2f sv;                                                            \
            sv = (v2f){s0, s0}; a0 = sv * a0 + c01; b0 = sv * b0 + c23;        \
            sv = (v2f){s1, s1}; a1 = sv * a1 + c01; b1 = sv * b1 + c23;        \
            sv = (v2f){s2, s2}; a2 = sv * a2 + c01; b2 = sv * b2 + c23;        \
            sv = (v2f){s3, s3}; a3 = sv * a3 + c01; b3 = sv * b3 + c23;        \
        }                                                                      \
        v4f o;                                                                 \
        o = (v4f){a0.x, a0.y, b0.x, b0.y};                                     \
        __builtin_nontemporal_store(o, Ovv + (IDXV));                          \
        o = (v4f){a1.x, a1.y, b1.x, b1.y};                                     \
        __builtin_nontemporal_store(o, Ovv + (IDXV) + BLOCK);                  \
        o = (v4f){a2.x, a2.y, b2.x, b2.y};                                     \
        __builtin_nontemporal_store(o, Ovv + (IDXV) + 2 * BLOCK);              \
        o = (v4f){a3.x, a3.y, b3.x, b3.y};                                     \
        __builtin_nontemporal_store(o, Ovv + (IDXV) + 3 * BLOCK);              \
    } while (0)

// ---------------------------------------------------------------------------
// Persistent main: each block owns T consecutive tiles, register-double-
// buffered (named A*/B* ping-pong). Tile t+1's global loads issue BEFORE
// tile t's ~800-instruction compute, so HBM latency and bandwidth hide under
// the VALU work instead of serializing in workgroup generations.
// launch_bounds(256,4): VGPR cap 128 (no forced spill), 4 wg/CU resident.
// ---------------------------------------------------------------------------
__global__ __launch_bounds__(BLOCK, 4) void radial_main(
    const float4* __restrict__ Xv,
    const float4* __restrict__ P,
    float4* __restrict__ Ov,
    int T)
{
    v4f* __restrict__ Ovv = (v4f*)Ov;     // native-vector alias for NT stores

    float4 z = P[2 * N_FLOWS];            // x0_0 (uniform -> s_load)
    v2f z01 = (v2f){z.x, z.y};
    v2f z23 = (v2f){z.z, z.w};

    const unsigned lane = threadIdx.x;
    unsigned idx = (unsigned)blockIdx.x * (unsigned)T * TILE + lane;

    float4 A0, A1, A2, A3, B0, B1, B2, B3;

    LOADT(A0, A1, A2, A3, idx);
    int t = 0;
    for (;;) {
        if (t + 1 < T) LOADT(B0, B1, B2, B3, idx + TILE);  // prefetch next tile
        COMPSTORE(A0, A1, A2, A3, idx);                    // compute + store current
        if (++t >= T) break;
        idx += TILE;
        if (t + 1 < T) LOADT(A0, A1, A2, A3, idx + TILE);
        COMPSTORE(B0, B1, B2, B3, idx);
        if (++t >= T) break;
        idx += TILE;
    }
}

// Generic tail: one guarded sample per thread (grid is 0 for BATCH=2^23).
__global__ void radial_tail(const float4* __restrict__ Xv,
                            const float4* __restrict__ P,
                            float4* __restrict__ Ov,
                            int start, int batch) {
    int idx = start + blockIdx.x * blockDim.x + threadIdx.x;
    if (idx >= batch) return;
    float4 z = P[2 * N_FLOWS];
    float4 v = Xv[idx];
    float dx = v.x - z.x, dy = v.y - z.y, dz = v.z - z.z, dw = v.w - z.w;
#pragma unroll
    for (int f = 0; f < N_FLOWS; ++f) {
        float4 c  = P[2 * f];
        float4 ab = P[2 * f + 1];
        float r2 = dx * dx + dy * dy + dz * dz + dw * dw;
        float r  = __builtin_amdgcn_sqrtf(r2);
        float s  = __builtin_fmaf(ab.y, __builtin_amdgcn_rcpf(ab.x + r), 1.0f);
        dx = s * dx + c.x; dy = s * dy + c.y;
        dz = s * dz + c.z; dw = s * dw + c.w;
    }
    float4 o; o.x = dx; o.y = dy; o.z = dz; o.w = dw;
    Ov[idx] = o;
}

extern "C" void kernel_launch(void* const* d_in, const int* in_sizes, int n_in,
                              void* d_out, int out_size, void* d_ws, size_t ws_size,
                              hipStream_t stream) {
    const float* X   = (const float*)d_in[0];
    const float* x0s = (const float*)d_in[1];
    const float* ap  = (const float*)d_in[2];
    const float* bp  = (const float*)d_in[3];
    float* out = (float*)d_out;
    float* ws  = (float*)d_ws;

    int batch = in_sizes[0] / DIM;     // 8388608
    int tiles = batch / TILE;          // 8192 for BATCH=2^23

    radial_setup<<<1, 64, 0, stream>>>(x0s, ap, bp, ws);

    int done = 0;
    if (tiles >= PBLOCKS) {
        int T = tiles / PBLOCKS;       // 8
        radial_main<<<PBLOCKS, BLOCK, 0, stream>>>(
            (const float4*)X, (const float4*)ws, (float4*)out, T);
        done = PBLOCKS * T * TILE;
    } else if (tiles > 0) {
        radial_main<<<tiles, BLOCK, 0, stream>>>(
            (const float4*)X, (const float4*)ws, (float4*)out, 1);
        done = tiles * TILE;
    }

    int rem = batch - done;
    if (rem > 0)
        radial_tail<<<(rem + 255) / 256, 256, 0, stream>>>(
            (const float4*)X, (const float4*)ws, (float4*)out, done, batch);
}

// Round 7
// 253.764 us; speedup vs baseline: 1.0069x; 1.0018x over previous
//
#include <hip/hip_runtime.h>

#define N_FLOWS 20
#define DIM 4
#define ITEMS 4            // samples per thread per tile (one rcp-quad per flow)
#define BLOCK 256
#define PBLOCKS 2048       // persistent blocks: 8 workgroups/CU on 256 CUs (TLP + prefetch)
#define TILE (BLOCK * ITEMS)   // 1024 float4 samples per tile

typedef float v2f __attribute__((ext_vector_type(2)));
typedef float v4f __attribute__((ext_vector_type(4)));   // native vector: OK for
                                                         // __builtin_nontemporal_store
                                                         // (HIP float4 class is NOT)

// ---------------------------------------------------------------------------
// Setup: one tiny block precomputes per-flow constants for the d-space
// recurrence. d_f := x - x0_f;  s = 1 + beta/(alpha + ||d_f||);
// d_{f+1} = s*d_f + c_f, with c_f = x0_f - x0_{f+1} (f<19), c_19 = x0_19
// so the final update directly produces x_20.
// ws layout per flow f (8 floats): [c.x,c.y,c.z,c.w, alpha, beta, 0, 0]
// slot f==N_FLOWS: [x0_0 (4 floats), 0,0,0,0]  (for d_0 init)
// ---------------------------------------------------------------------------
__global__ void radial_setup(const float* __restrict__ x0s,
                             const float* __restrict__ alpha_primes,
                             const float* __restrict__ beta_primes,
                             float* __restrict__ ws) {
    int f = threadIdx.x;
    if (f < N_FLOWS) {
        float alpha = __logf(1.0f + __expf(alpha_primes[f]));
        float beta  = __logf(1.0f + __expf(beta_primes[f])) - alpha;
        float* p = ws + 8 * f;
        const bool last = (f == N_FLOWS - 1);
#pragma unroll
        for (int j = 0; j < 4; ++j)
            p[j] = x0s[4 * f + j] - (last ? 0.0f : x0s[4 * (f + 1) + j]);
        p[4] = alpha;
        p[5] = beta;
        p[6] = 0.0f;
        p[7] = 0.0f;
    } else if (f == N_FLOWS) {
        float* p = ws + 8 * N_FLOWS;
        p[0] = x0s[0]; p[1] = x0s[1]; p[2] = x0s[2]; p[3] = x0s[3];
        p[4] = 0.0f; p[5] = 0.0f; p[6] = 0.0f; p[7] = 0.0f;
    }
}

// ---------------------------------------------------------------------------
// Everything macro-expanded into ONE function scope with NAMED variables:
// no local arrays, no array-reference args -> nothing for SROA to miss,
// buffers provably live in VGPRs (round-2 lesson: the by-reference array
// version went to scratch, +57 MB of spill traffic, zero speedup).
// Round-3 lesson: no token-pasting before member access; round-4 lesson:
// NT stores need native clang vectors, not HIP_vector_type.
// Round-5 lesson: VGPR=36 (prefetch materialized) but launch_bounds(256,4)
// + 1024 blocks delivered only 29% occupancy -> vmcnt waits unhidden.
// ---------------------------------------------------------------------------

// Load one tile into named buffer regs V0..V3.
#define LOADT(V0, V1, V2, V3, IDXV)               \
    do {                                          \
        V0 = Xv[(IDXV)];                          \
        V1 = Xv[(IDXV) + BLOCK];                  \
        V2 = Xv[(IDXV) + 2 * BLOCK];              \
        V3 = Xv[(IDXV) + 3 * BLOCK];              \
    } while (0)

// Run the 20-flow chain on buffer V0..V3 and store results (non-temporal:
// output is never re-read; keep it from evicting the L3-resident input).
// Per flow: 4x {pk_mul, pk_fma, add, v_sqrt, add} to form D_i = alpha + r_i,
// one shared v_rcp via quad batch-inversion (9 muls), 4x {fma, 2x pk_fma}.
#define COMPSTORE(V0, V1, V2, V3, IDXV)                                        \
    do {                                                                       \
        v2f a0 = (v2f){V0.x, V0.y} - z01;                                      \
        v2f b0 = (v2f){V0.z, V0.w} - z23;                                      \
        v2f a1 = (v2f){V1.x, V1.y} - z01;                                      \
        v2f b1 = (v2f){V1.z, V1.w} - z23;                                      \
        v2f a2 = (v2f){V2.x, V2.y} - z01;                                      \
        v2f b2 = (v2f){V2.z, V2.w} - z23;                                      \
        v2f a3 = (v2f){V3.x, V3.y} - z01;                                      \
        v2f b3 = (v2f){V3.z, V3.w} - z23;                                      \
        _Pragma("unroll")                                                      \
        for (int f = 0; f < N_FLOWS; ++f) {                                    \
            float4 c  = P[2 * f];        /* uniform -> s_load */               \
            float4 ab = P[2 * f + 1];                                          \
            v2f c01 = (v2f){c.x, c.y};                                         \
            v2f c23 = (v2f){c.z, c.w};                                         \
            float alpha = ab.x, beta = ab.y;                                   \
            v2f q0 = a0 * a0; q0 += b0 * b0;                                   \
            v2f q1 = a1 * a1; q1 += b1 * b1;                                   \
            v2f q2 = a2 * a2; q2 += b2 * b2;                                   \
            v2f q3 = a3 * a3; q3 += b3 * b3;                                   \
            float D0 = alpha + __builtin_amdgcn_sqrtf(q0.x + q0.y);            \
            float D1 = alpha + __builtin_amdgcn_sqrtf(q1.x + q1.y);            \
            float D2 = alpha + __builtin_amdgcn_sqrtf(q2.x + q2.y);            \
            float D3 = alpha + __builtin_amdgcn_sqrtf(q3.x + q3.y);            \
            float p1  = D0 * D1;                                               \
            float p2  = p1 * D2;                                               \
            float p3  = p2 * D3;                                               \
            float inv = __builtin_amdgcn_rcpf(p3);                             \
            float i3 = inv * p2;        /* 1/D3 */                             \
            float w2 = inv * D3;        /* 1/(D0 D1 D2) */                     \
            float i2 = w2 * p1;         /* 1/D2 */                             \
            float w1 = w2 * D2;         /* 1/(D0 D1) */                        \
            float i1 = w1 * D0;         /* 1/D1 */                             \
            float i0 = w1 * D1;         /* 1/D0 */                             \
            float s0 = __builtin_fmaf(beta, i0, 1.0f);                         \
            float s1 = __builtin_fmaf(beta, i1, 1.0f);                         \
            float s2 = __builtin_fmaf(beta, i2, 1.0f);                         \
            float s3 = __builtin_fmaf(beta, i3, 1.0f);                         \
            v2f sv;                                                            \
            sv = (v2f){s0, s0}; a0 = sv * a0 + c01; b0 = sv * b0 + c23;        \
            sv = (v2f){s1, s1}; a1 = sv * a1 + c01; b1 = sv * b1 + c23;        \
            sv = (v2f){s2, s2}; a2 = sv * a2 + c01; b2 = sv * b2 + c23;        \
            sv = (v2f){s3, s3}; a3 = sv * a3 + c01; b3 = sv * b3 + c23;        \
        }                                                                      \
        v4f o;                                                                 \
        o = (v4f){a0.x, a0.y, b0.x, b0.y};                                     \
        __builtin_nontemporal_store(o, Ovv + (IDXV));                          \
        o = (v4f){a1.x, a1.y, b1.x, b1.y};                                     \
        __builtin_nontemporal_store(o, Ovv + (IDXV) + BLOCK);                  \
        o = (v4f){a2.x, a2.y, b2.x, b2.y};                                     \
        __builtin_nontemporal_store(o, Ovv + (IDXV) + 2 * BLOCK);              \
        o = (v4f){a3.x, a3.y, b3.x, b3.y};                                     \
        __builtin_nontemporal_store(o, Ovv + (IDXV) + 3 * BLOCK);              \
    } while (0)

// ---------------------------------------------------------------------------
// Persistent main: each block owns T consecutive tiles, register-double-
// buffered (named A*/B* ping-pong). Tile t+1's global loads issue BEFORE
// tile t's compute. Round-6: 2048 blocks (8/CU) + no min-waves clamp so the
// hardware can keep 8 waves/SIMD resident (VGPR=36 permits it) -- the TLP
// that round-5's 29%-occupancy config lacked to hide the per-tile vmcnt
// waits (B-load wait + store-completion waits from tight reg reuse).
// ---------------------------------------------------------------------------
__global__ __launch_bounds__(BLOCK) void radial_main(
    const float4* __restrict__ Xv,
    const float4* __restrict__ P,
    float4* __restrict__ Ov,
    int T)
{
    v4f* __restrict__ Ovv = (v4f*)Ov;     // native-vector alias for NT stores

    float4 z = P[2 * N_FLOWS];            // x0_0 (uniform -> s_load)
    v2f z01 = (v2f){z.x, z.y};
    v2f z23 = (v2f){z.z, z.w};

    const unsigned lane = threadIdx.x;
    unsigned idx = (unsigned)blockIdx.x * (unsigned)T * TILE + lane;

    float4 A0, A1, A2, A3, B0, B1, B2, B3;

    LOADT(A0, A1, A2, A3, idx);
    int t = 0;
    for (;;) {
        if (t + 1 < T) LOADT(B0, B1, B2, B3, idx + TILE);  // prefetch next tile
        COMPSTORE(A0, A1, A2, A3, idx);                    // compute + store current
        if (++t >= T) break;
        idx += TILE;
        if (t + 1 < T) LOADT(A0, A1, A2, A3, idx + TILE);
        COMPSTORE(B0, B1, B2, B3, idx);
        if (++t >= T) break;
        idx += TILE;
    }
}

// Generic tail: one guarded sample per thread (grid is 0 for BATCH=2^23).
__global__ void radial_tail(const float4* __restrict__ Xv,
                            const float4* __restrict__ P,
                            float4* __restrict__ Ov,
                            int start, int batch) {
    int idx = start + blockIdx.x * blockDim.x + threadIdx.x;
    if (idx >= batch) return;
    float4 z = P[2 * N_FLOWS];
    float4 v = Xv[idx];
    float dx = v.x - z.x, dy = v.y - z.y, dz = v.z - z.z, dw = v.w - z.w;
#pragma unroll
    for (int f = 0; f < N_FLOWS; ++f) {
        float4 c  = P[2 * f];
        float4 ab = P[2 * f + 1];
        float r2 = dx * dx + dy * dy + dz * dz + dw * dw;
        float r  = __builtin_amdgcn_sqrtf(r2);
        float s  = __builtin_fmaf(ab.y, __builtin_amdgcn_rcpf(ab.x + r), 1.0f);
        dx = s * dx + c.x; dy = s * dy + c.y;
        dz = s * dz + c.z; dw = s * dw + c.w;
    }
    float4 o; o.x = dx; o.y = dy; o.z = dz; o.w = dw;
    Ov[idx] = o;
}

extern "C" void kernel_launch(void* const* d_in, const int* in_sizes, int n_in,
                              void* d_out, int out_size, void* d_ws, size_t ws_size,
                              hipStream_t stream) {
    const float* X   = (const float*)d_in[0];
    const float* x0s = (const float*)d_in[1];
    const float* ap  = (const float*)d_in[2];
    const float* bp  = (const float*)d_in[3];
    float* out = (float*)d_out;
    float* ws  = (float*)d_ws;

    int batch = in_sizes[0] / DIM;     // 8388608
    int tiles = batch / TILE;          // 8192 for BATCH=2^23

    radial_setup<<<1, 64, 0, stream>>>(x0s, ap, bp, ws);

    int done = 0;
    if (tiles >= PBLOCKS) {
        int T = tiles / PBLOCKS;       // 4
        radial_main<<<PBLOCKS, BLOCK, 0, stream>>>(
            (const float4*)X, (const float4*)ws, (float4*)out, T);
        done = PBLOCKS * T * TILE;
    } else if (tiles > 0) {
        radial_main<<<tiles, BLOCK, 0, stream>>>(
            (const float4*)X, (const float4*)ws, (float4*)out, 1);
        done = tiles * TILE;
    }

    int rem = batch - done;
    if (rem > 0)
        radial_tail<<<(rem + 255) / 256, 256, 0, stream>>>(
            (const float4*)X, (const float4*)ws, (float4*)out, done, batch);
}

// Round 8
// 248.910 us; speedup vs baseline: 1.0266x; 1.0195x over previous
//
#include <hip/hip_runtime.h>

#define N_FLOWS 20
#define DIM 4
#define ITEMS 4            // samples per thread per tile (one rcp-quad per flow)
#define BLOCK 256
#define PBLOCKS 2048       // persistent blocks: 8 workgroups/CU on 256 CUs
#define TILE (BLOCK * ITEMS)   // 1024 float4 samples per tile

typedef float v2f __attribute__((ext_vector_type(2)));
typedef float v4f __attribute__((ext_vector_type(4)));   // native vector: OK for
                                                         // __builtin_nontemporal_store

// sched_barrier(0): no instruction may cross -> pins each prefetch load at its
// source position instead of letting the compiler re-hoist them into one burst.
#define SB __builtin_amdgcn_sched_barrier(0)

// ---------------------------------------------------------------------------
// Setup: one tiny block precomputes per-flow constants for the d-space
// recurrence. d_f := x - x0_f;  s = 1 + beta/(alpha + ||d_f||);
// d_{f+1} = s*d_f + c_f, with c_f = x0_f - x0_{f+1} (f<19), c_19 = x0_19
// so the final update directly produces x_20.
// ws layout per flow f (8 floats): [c.x,c.y,c.z,c.w, alpha, beta, 0, 0]
// slot f==N_FLOWS: [x0_0 (4 floats), 0,0,0,0]  (for d_0 init)
// ---------------------------------------------------------------------------
__global__ void radial_setup(const float* __restrict__ x0s,
                             const float* __restrict__ alpha_primes,
                             const float* __restrict__ beta_primes,
                             float* __restrict__ ws) {
    int f = threadIdx.x;
    if (f < N_FLOWS) {
        float alpha = __logf(1.0f + __expf(alpha_primes[f]));
        float beta  = __logf(1.0f + __expf(beta_primes[f])) - alpha;
        float* p = ws + 8 * f;
        const bool last = (f == N_FLOWS - 1);
#pragma unroll
        for (int j = 0; j < 4; ++j)
            p[j] = x0s[4 * f + j] - (last ? 0.0f : x0s[4 * (f + 1) + j]);
        p[4] = alpha;
        p[5] = beta;
        p[6] = 0.0f;
        p[7] = 0.0f;
    } else if (f == N_FLOWS) {
        float* p = ws + 8 * N_FLOWS;
        p[0] = x0s[0]; p[1] = x0s[1]; p[2] = x0s[2]; p[3] = x0s[3];
        p[4] = 0.0f; p[5] = 0.0f; p[6] = 0.0f; p[7] = 0.0f;
    }
}

// ---------------------------------------------------------------------------
// One flow applied to the resident quad (a0..a3, b0..b3 in enclosing scope).
// 4x {pk_mul, pk_fma, add, v_sqrt, add} -> D_i, one shared v_rcp via quad
// batch-inversion (9 muls), then 4x {fma, 2x pk_fma}.
// ---------------------------------------------------------------------------
#define FLOWQ(F)                                                               \
    do {                                                                       \
        float4 c  = P[2 * (F)];        /* uniform -> s_load */                 \
        float4 ab = P[2 * (F) + 1];                                            \
        v2f c01 = (v2f){c.x, c.y};                                             \
        v2f c23 = (v2f){c.z, c.w};                                             \
        float alpha = ab.x, beta = ab.y;                                       \
        v2f q0 = a0 * a0; q0 += b0 * b0;                                       \
        v2f q1 = a1 * a1; q1 += b1 * b1;                                       \
        v2f q2 = a2 * a2; q2 += b2 * b2;                                       \
        v2f q3 = a3 * a3; q3 += b3 * b3;                                       \
        float D0 = alpha + __builtin_amdgcn_sqrtf(q0.x + q0.y);                \
        float D1 = alpha + __builtin_amdgcn_sqrtf(q1.x + q1.y);                \
        float D2 = alpha + __builtin_amdgcn_sqrtf(q2.x + q2.y);                \
        float D3 = alpha + __builtin_amdgcn_sqrtf(q3.x + q3.y);                \
        float p1  = D0 * D1;                                                   \
        float p2  = p1 * D2;                                                   \
        float p3  = p2 * D3;                                                   \
        float inv = __builtin_amdgcn_rcpf(p3);                                 \
        float i3 = inv * p2;        /* 1/D3 */                                 \
        float w2 = inv * D3;        /* 1/(D0 D1 D2) */                         \
        float i2 = w2 * p1;         /* 1/D2 */                                 \
        float w1 = w2 * D2;         /* 1/(D0 D1) */                            \
        float i1 = w1 * D0;         /* 1/D1 */                                 \
        float i0 = w1 * D1;         /* 1/D0 */                                 \
        float s0 = __builtin_fmaf(beta, i0, 1.0f);                             \
        float s1 = __builtin_fmaf(beta, i1, 1.0f);                             \
        float s2 = __builtin_fmaf(beta, i2, 1.0f);                             \
        float s3 = __builtin_fmaf(beta, i3, 1.0f);                             \
        v2f sv;                                                                \
        sv = (v2f){s0, s0}; a0 = sv * a0 + c01; b0 = sv * b0 + c23;            \
        sv = (v2f){s1, s1}; a1 = sv * a1 + c01; b1 = sv * b1 + c23;            \
        sv = (v2f){s2, s2}; a2 = sv * a2 + c01; b2 = sv * b2 + c23;            \
        sv = (v2f){s3, s3}; a3 = sv * a3 + c01; b3 = sv * b3 + c23;            \
    } while (0)

// d_0 = x - x0_0; the buffer regs die here (freed for the next prefetch).
#define DINIT(V0, V1, V2, V3)                                                  \
    do {                                                                       \
        a0 = (v2f){V0.x, V0.y} - z01; b0 = (v2f){V0.z, V0.w} - z23;            \
        a1 = (v2f){V1.x, V1.y} - z01; b1 = (v2f){V1.z, V1.w} - z23;            \
        a2 = (v2f){V2.x, V2.y} - z01; b2 = (v2f){V2.z, V2.w} - z23;            \
        a3 = (v2f){V3.x, V3.y} - z01; b3 = (v2f){V3.z, V3.w} - z23;            \
    } while (0)

// Non-temporal stores: output is never re-read.
#define STORES(IDXV)                                                           \
    do {                                                                       \
        v4f o;                                                                 \
        o = (v4f){a0.x, a0.y, b0.x, b0.y};                                     \
        __builtin_nontemporal_store(o, Ovv + (IDXV));                          \
        o = (v4f){a1.x, a1.y, b1.x, b1.y};                                     \
        __builtin_nontemporal_store(o, Ovv + (IDXV) + BLOCK);                  \
        o = (v4f){a2.x, a2.y, b2.x, b2.y};                                     \
        __builtin_nontemporal_store(o, Ovv + (IDXV) + 2 * BLOCK);              \
        o = (v4f){a3.x, a3.y, b3.x, b3.y};                                     \
        __builtin_nontemporal_store(o, Ovv + (IDXV) + 3 * BLOCK);              \
    } while (0)

// One tile phase: compute 20 flows on CUR buffer while issuing the 4 prefetch
// loads of the NEXT tile spread through the flow chain (after flows 0/5/10/15),
// each pinned with sched_barrier(0) so the CU's load traffic is continuous
// (~1 KB per wave every ~770 cy) instead of a queue-depth-capped burst.
// Round-7 lesson: wall pinned at 94us across occ 29-66% -> not occupancy;
// time-averaged outstanding bytes ~3 KB/CU (burst duty cycle) matches the
// measured 3.4 B/cy/CU exactly. This phase structure raises the duty cycle.
#define PHASE(V0, V1, V2, V3, N0, N1, N2, N3)                                  \
    do {                                                                       \
        unsigned nidx = idx + ((t + 1 < T) ? (unsigned)TILE : 0u);             \
        DINIT(V0, V1, V2, V3);                                                 \
        FLOWQ(0);                                                              \
        SB; N0 = Xv[nidx]; SB;                                                 \
        FLOWQ(1); FLOWQ(2); FLOWQ(3); FLOWQ(4); FLOWQ(5);                      \
        SB; N1 = Xv[nidx + BLOCK]; SB;                                         \
        FLOWQ(6); FLOWQ(7); FLOWQ(8); FLOWQ(9); FLOWQ(10);                     \
        SB; N2 = Xv[nidx + 2 * BLOCK]; SB;                                     \
        FLOWQ(11); FLOWQ(12); FLOWQ(13); FLOWQ(14); FLOWQ(15);                 \
        SB; N3 = Xv[nidx + 3 * BLOCK]; SB;                                     \
        FLOWQ(16); FLOWQ(17); FLOWQ(18); FLOWQ(19);                            \
        STORES(idx);                                                           \
    } while (0)

// ---------------------------------------------------------------------------
// Persistent main: each block owns T consecutive tiles, register-double-
// buffered (named A*/B* ping-pong), prefetch loads spread through compute.
// ---------------------------------------------------------------------------
__global__ __launch_bounds__(BLOCK) void radial_main(
    const float4* __restrict__ Xv,
    const float4* __restrict__ P,
    float4* __restrict__ Ov,
    int T)
{
    v4f* __restrict__ Ovv = (v4f*)Ov;     // native-vector alias for NT stores

    float4 z = P[2 * N_FLOWS];            // x0_0 (uniform -> s_load)
    v2f z01 = (v2f){z.x, z.y};
    v2f z23 = (v2f){z.z, z.w};

    const unsigned lane = threadIdx.x;
    unsigned idx = (unsigned)blockIdx.x * (unsigned)T * TILE + lane;

    float4 A0, A1, A2, A3, B0, B1, B2, B3;
    v2f a0, a1, a2, a3, b0, b1, b2, b3;

    A0 = Xv[idx];
    A1 = Xv[idx + BLOCK];
    A2 = Xv[idx + 2 * BLOCK];
    A3 = Xv[idx + 3 * BLOCK];

    int t = 0;
    for (;;) {
        PHASE(A0, A1, A2, A3, B0, B1, B2, B3);
        if (++t >= T) break;
        idx += TILE;
        PHASE(B0, B1, B2, B3, A0, A1, A2, A3);
        if (++t >= T) break;
        idx += TILE;
    }
}

// Generic tail: one guarded sample per thread (grid is 0 for BATCH=2^23).
__global__ void radial_tail(const float4* __restrict__ Xv,
                            const float4* __restrict__ P,
                            float4* __restrict__ Ov,
                            int start, int batch) {
    int idx = start + blockIdx.x * blockDim.x + threadIdx.x;
    if (idx >= batch) return;
    float4 z = P[2 * N_FLOWS];
    float4 v = Xv[idx];
    float dx = v.x - z.x, dy = v.y - z.y, dz = v.z - z.z, dw = v.w - z.w;
#pragma unroll
    for (int f = 0; f < N_FLOWS; ++f) {
        float4 c  = P[2 * f];
        float4 ab = P[2 * f + 1];
        float r2 = dx * dx + dy * dy + dz * dz + dw * dw;
        float r  = __builtin_amdgcn_sqrtf(r2);
        float s  = __builtin_fmaf(ab.y, __builtin_amdgcn_rcpf(ab.x + r), 1.0f);
        dx = s * dx + c.x; dy = s * dy + c.y;
        dz = s * dz + c.z; dw = s * dw + c.w;
    }
    float4 o; o.x = dx; o.y = dy; o.z = dz; o.w = dw;
    Ov[idx] = o;
}

extern "C" void kernel_launch(void* const* d_in, const int* in_sizes, int n_in,
                              void* d_out, int out_size, void* d_ws, size_t ws_size,
                              hipStream_t stream) {
    const float* X   = (const float*)d_in[0];
    const float* x0s = (const float*)d_in[1];
    const float* ap  = (const float*)d_in[2];
    const float* bp  = (const float*)d_in[3];
    float* out = (float*)d_out;
    float* ws  = (float*)d_ws;

    int batch = in_sizes[0] / DIM;     // 8388608
    int tiles = batch / TILE;          // 8192 for BATCH=2^23

    radial_setup<<<1, 64, 0, stream>>>(x0s, ap, bp, ws);

    int done = 0;
    if (tiles >= PBLOCKS) {
        int T = tiles / PBLOCKS;       // 4
        radial_main<<<PBLOCKS, BLOCK, 0, stream>>>(
            (const float4*)X, (const float4*)ws, (float4*)out, T);
        done = PBLOCKS * T * TILE;
    } else if (tiles > 0) {
        radial_main<<<tiles, BLOCK, 0, stream>>>(
            (const float4*)X, (const float4*)ws, (float4*)out, 1);
        done = tiles * TILE;
    }

    int rem = batch - done;
    if (rem > 0)
        radial_tail<<<(rem + 255) / 256, 256, 0, stream>>>(
            (const float4*)X, (const float4*)ws, (float4*)out, done, batch);
}